// Round 12
// baseline (80.638 us; speedup 1.0000x reference)
//
#include <hip/hip_runtime.h>

#define B_ 16
#define NP 784
#define D_ 256
#define NH_ 8
#define HD_ 32
#define KEMB 192
#define SCALE_ 0.17677669529663687f
#define LOG2E_ 1.4426950408889634f

typedef __attribute__((ext_vector_type(4))) float f32x4;
typedef __attribute__((ext_vector_type(8))) short bf16x8;
typedef __attribute__((ext_vector_type(4))) short bf16x4;

__device__ __forceinline__ unsigned short f2bf(float f) {
    union { float f; unsigned int u; } v; v.f = f;
    unsigned int u = v.u;
    unsigned int r = (u + 0x7fffu + ((u >> 16) & 1u)) >> 16;
    return (unsigned short)r;
}

__device__ __forceinline__ unsigned int cvtpk(float a, float b) {
    unsigned int r;
    asm("v_cvt_pk_bf16_f32 %0, %1, %2" : "=v"(r) : "v"(a), "v"(b));
    return r;
}

__device__ __forceinline__ float fexp2(float x) {
#if __has_builtin(__builtin_amdgcn_exp2f)
    return __builtin_amdgcn_exp2f(x);
#else
    return exp2f(x);
#endif
}

// async global->LDS, 16B per lane; LDS dest = wave-uniform base + lane*16
__device__ __forceinline__ void gl_lds16(const unsigned short* g, unsigned short* l) {
    __builtin_amdgcn_global_load_lds(
        (const __attribute__((address_space(1))) unsigned int*)(const void*)g,
        (__attribute__((address_space(3))) unsigned int*)(void*)l, 16, 0, 0);
}

// ---------------- conv GEMM + prep tails: grid (1157) ----------------
__global__ __launch_bounds__(256) void conv_prep(
    const float* __restrict__ cur, const float* __restrict__ prev,
    const float* __restrict__ conv_w32, const float* __restrict__ bias,
    const float* __restrict__ q_w32, const float* __restrict__ kv_w32,
    const float* __restrict__ pr_w32,
    unsigned short* __restrict__ w_q, unsigned short* __restrict__ w_kv,
    unsigned short* __restrict__ w_pr,
    const float* __restrict__ bt, float* __restrict__ bto,
    unsigned short* __restrict__ outp)
{
    const int tid = threadIdx.x;
    if (blockIdx.x >= 784) {
        int bi = blockIdx.x - 784;
        if (bi < 256) {
            int i = (bi * 256 + tid) * 4;          // 262144 floats total
            const float* s; unsigned short* dp; int off;
            if (i < 65536)       { s = q_w32;  dp = w_q;  off = i; }
            else if (i < 196608) { s = kv_w32; dp = w_kv; off = i - 65536; }
            else                 { s = pr_w32; dp = w_pr; off = i - 196608; }
            float4 v = *(const float4*)(s + off);
            dp[off + 0] = f2bf(v.x); dp[off + 1] = f2bf(v.y);
            dp[off + 2] = f2bf(v.z); dp[off + 3] = f2bf(v.w);
        } else {
            int i = (bi - 256) * 256 + tid;        // < 29952
            if (i < 29768) {
                int h = i / 3721, idx = i - h * 3721;
                bto[i] = bt[idx * NH_ + h] * LOG2E_;
            }
        }
        return;
    }
    __shared__ __align__(16) unsigned short At[32 * 64];
    __shared__ __align__(16) unsigned short Bt[256 * 64];
    const int lane = tid & 63, wid = tid >> 6;
    const int lo = lane & 15, hi = lane >> 4;
    const int m0 = blockIdx.x * 32;
    // hoisted im2col A-source address (1 task/thread)
    const float* asrc;
    unsigned short* adst;
    {
        int row = tid >> 3, seg = tid & 7;
        int m = m0 + row;
        int fb = m / NP, n = m - fb * NP;
        int py = n / 28, px = n - py * 28;
        const float* F = (fb >= 16 ? prev + (size_t)(fb - 16) * 150528 : cur + (size_t)fb * 150528);
        asrc = F + (py * 8 + seg) * 224 + px * 8;
        adst = At + row * 64 + ((seg ^ (row & 7)) * 8);
    }
    f32x4 acc[2][4] = {};
#pragma unroll
    for (int kt = 0; kt < 3; ++kt) {
        __syncthreads();
        // B: 256x64 panel from fp32 weights, reg-staged + cvt
#pragma unroll
        for (int i = 0; i < 8; ++i) {
            int s = i * 256 + tid;
            int row = s >> 3, j = s & 7, seg = j ^ (row & 7);
            const float* wsrc = conv_w32 + row * KEMB + kt * 64 + seg * 8;
            float4 b0 = *(const float4*)(wsrc);
            float4 b1 = *(const float4*)(wsrc + 4);
            union { unsigned int u[4]; bf16x8 v; } bv;
            bv.u[0] = cvtpk(b0.x, b0.y); bv.u[1] = cvtpk(b0.z, b0.w);
            bv.u[2] = cvtpk(b1.x, b1.y); bv.u[3] = cvtpk(b1.z, b1.w);
            *(bf16x8*)(void*)(Bt + row * 64 + j * 8) = bv.v;
        }
        // A: reg-staged from frames (channel kt), swizzled ds_write
        {
            const float* src = asrc + kt * 50176;
            float4 a0 = *(const float4*)(src);
            float4 a1 = *(const float4*)(src + 4);
            union { unsigned int u[4]; bf16x8 v; } ov;
            ov.u[0] = cvtpk(a0.x, a0.y); ov.u[1] = cvtpk(a0.z, a0.w);
            ov.u[2] = cvtpk(a1.x, a1.y); ov.u[3] = cvtpk(a1.z, a1.w);
            *(bf16x8*)(void*)(adst) = ov.v;
        }
        __syncthreads();
#pragma unroll
        for (int kk = 0; kk < 2; ++kk) {
            bf16x8 af[2], bfv[4];
#pragma unroll
            for (int f = 0; f < 2; ++f) {
                int rowa = f * 16 + lo;
                af[f] = *(const bf16x8*)(const void*)(At + rowa * 64 + (((kk * 4 + hi) ^ (rowa & 7)) * 8));
            }
#pragma unroll
            for (int f = 0; f < 4; ++f) {
                int rowb = wid * 64 + f * 16 + lo;
                bfv[f] = *(const bf16x8*)(const void*)(Bt + rowb * 64 + (((kk * 4 + hi) ^ (rowb & 7)) * 8));
            }
#pragma unroll
            for (int fr = 0; fr < 2; ++fr)
#pragma unroll
                for (int fc = 0; fc < 4; ++fc)
                    acc[fr][fc] = __builtin_amdgcn_mfma_f32_16x16x32_bf16(af[fr], bfv[fc], acc[fr][fc], 0, 0, 0);
        }
    }
#pragma unroll
    for (int fr = 0; fr < 2; ++fr)
#pragma unroll
        for (int fc = 0; fc < 4; ++fc)
#pragma unroll
            for (int r = 0; r < 4; ++r) {
                int m = m0 + fr * 16 + hi * 4 + r;
                int c = wid * 64 + fc * 16 + lo;
                outp[(size_t)m * D_ + c] = f2bf(acc[fr][fc][r] + bias[c]);
            }
}

// ---------------- fused Q + KV projection: 128^2 tile, grid (98, 6) ----------------
__global__ __launch_bounds__(256) void gemm_qkv(
    const unsigned short* __restrict__ emb,
    const unsigned short* __restrict__ w_q, const float* __restrict__ q_b,
    const unsigned short* __restrict__ w_kv, const float* __restrict__ kv_b,
    unsigned short* __restrict__ q_h, unsigned short* __restrict__ k_h,
    unsigned short* __restrict__ v_t)
{
    __shared__ __align__(16) unsigned short At[128 * 64];
    __shared__ __align__(16) unsigned short Bt[128 * 64];
    const int tid = threadIdx.x;
    const int lo = tid & 15, hi = (tid >> 4) & 3, wid = tid >> 6;
    const int m0 = blockIdx.x * 128;
    const int y = blockIdx.y;
    const bool iskv = y >= 2;
    const unsigned short* Abase = iskv ? emb + (size_t)12544 * D_ : emb;   // kv uses PREV-frame emb
    const unsigned short* W = iskv ? w_kv : w_q;
    const float* bias = iskv ? kv_b : q_b;
    const int n0 = (iskv ? y - 2 : y) * 128;
    const int wr = wid >> 1, wc = wid & 1;
    const int wvb = wid * 512;
    f32x4 acc[4][4] = {};
#pragma unroll
    for (int kt = 0; kt < 4; ++kt) {
        const int k0 = kt * 64;
        __syncthreads();
#pragma unroll
        for (int i = 0; i < 4; ++i) {
            int s = i * 256 + tid;
            int row = s >> 3, seg = (s & 7) ^ (row & 7);
            gl_lds16(Abase + (size_t)(m0 + row) * D_ + k0 + seg * 8, At + i * 2048 + wvb);
            gl_lds16(W + (size_t)(n0 + row) * D_ + k0 + seg * 8, Bt + i * 2048 + wvb);
        }
        __syncthreads();
#pragma unroll
        for (int kk = 0; kk < 2; ++kk) {
            bf16x8 af[4], bfv[4];
#pragma unroll
            for (int f = 0; f < 4; ++f) {
                int rowa = wr * 64 + f * 16 + lo;
                af[f] = *(const bf16x8*)(const void*)(At + rowa * 64 + (((kk * 4 + hi) ^ (rowa & 7)) * 8));
                int rowb = wc * 64 + f * 16 + lo;
                bfv[f] = *(const bf16x8*)(const void*)(Bt + rowb * 64 + (((kk * 4 + hi) ^ (rowb & 7)) * 8));
            }
#pragma unroll
            for (int fr = 0; fr < 4; ++fr)
#pragma unroll
                for (int fc = 0; fc < 4; ++fc)
                    acc[fr][fc] = __builtin_amdgcn_mfma_f32_16x16x32_bf16(af[fr], bfv[fc], acc[fr][fc], 0, 0, 0);
        }
    }
#pragma unroll
    for (int fr = 0; fr < 4; ++fr)
#pragma unroll
        for (int fc = 0; fc < 4; ++fc)
#pragma unroll
            for (int r = 0; r < 4; ++r) {
                int m = m0 + wr * 64 + fr * 16 + hi * 4 + r;
                int c = n0 + wc * 64 + fc * 16 + lo;
                float val = acc[fr][fc][r] + bias[c];
                int b = m / NP, n = m - (m / NP) * NP;
                if (!iskv) {
                    int h = c >> 5, d = c & 31;
                    q_h[(((size_t)(b * NH_ + h)) * NP + n) * HD_ + d] = f2bf(val * (SCALE_ * LOG2E_));
                } else if (c < D_) {
                    int h = c >> 5, d = c & 31;
                    k_h[(((size_t)(b * NH_ + h)) * NP + n) * HD_ + d] = f2bf(val);
                } else {
                    int cc = c - D_; int h = cc >> 5, d = cc & 31;
                    v_t[(((size_t)(b * NH_ + h)) * HD_ + d) * NP + n] = f2bf(val);
                }
            }
}

// ---------------- proj GEMM: 32M x 128N tile, fp32 out, grid (392, 2) ----------------
__global__ __launch_bounds__(256) void gemm_px(
    const unsigned short* __restrict__ A, const unsigned short* __restrict__ W,
    const float* __restrict__ bias, float* __restrict__ outp)
{
    __shared__ __align__(16) unsigned short At[32 * 64];
    __shared__ __align__(16) unsigned short Bt[128 * 64];
    const int tid = threadIdx.x;
    const int lo = tid & 15, hi = (tid >> 4) & 3, wid = tid >> 6;
    const int m0 = blockIdx.x * 32, n0 = blockIdx.y * 128;
    const int wr = wid >> 1, wc = wid & 1;
    const int wvb = wid * 512;
    f32x4 acc[4] = {};
#pragma unroll
    for (int kt = 0; kt < 4; ++kt) {
        const int k0 = kt * 64;
        __syncthreads();
        {
            int row = tid >> 3, seg = (tid & 7) ^ ((tid >> 3) & 7);
            gl_lds16(A + (size_t)(m0 + row) * D_ + k0 + seg * 8, At + wvb);
        }
#pragma unroll
        for (int i = 0; i < 4; ++i) {
            int s = i * 256 + tid;
            int row = s >> 3, seg = (s & 7) ^ (row & 7);
            gl_lds16(W + (size_t)(n0 + row) * D_ + k0 + seg * 8, Bt + i * 2048 + wvb);
        }
        __syncthreads();
#pragma unroll
        for (int kk = 0; kk < 2; ++kk) {
            bf16x8 af, bfv[4];
            {
                int rowa = wr * 16 + lo;
                af = *(const bf16x8*)(const void*)(At + rowa * 64 + (((kk * 4 + hi) ^ (rowa & 7)) * 8));
            }
#pragma unroll
            for (int f = 0; f < 4; ++f) {
                int rowb = wc * 64 + f * 16 + lo;
                bfv[f] = *(const bf16x8*)(const void*)(Bt + rowb * 64 + (((kk * 4 + hi) ^ (rowb & 7)) * 8));
            }
#pragma unroll
            for (int fc = 0; fc < 4; ++fc)
                acc[fc] = __builtin_amdgcn_mfma_f32_16x16x32_bf16(af, bfv[fc], acc[fc], 0, 0, 0);
        }
    }
#pragma unroll
    for (int fc = 0; fc < 4; ++fc)
#pragma unroll
        for (int r = 0; r < 4; ++r) {
            int m = m0 + wr * 16 + hi * 4 + r;
            int c = n0 + wc * 64 + fc * 16 + lo;
            outp[(size_t)m * D_ + c] = acc[fc][r] + bias[c];
        }
}

// ---------------- attention: q-doubled waves, grid 512 (R10-verified) + setprio ------
// Single change vs R10: s_setprio(1) around the MFMA clusters (T5). R10's waves have
// role diversity (waves 3-6 carry V issue/stage; waves drift within phases), the
// regime where m191 measured +4-7% on attention. Values bit-identical.
__global__ __launch_bounds__(448) void attn_k(
    const unsigned short* __restrict__ qh, const unsigned short* __restrict__ kh,
    const unsigned short* __restrict__ vt, const float* __restrict__ bias_t,
    const int* __restrict__ cpos, const int* __restrict__ ppos,
    unsigned short* __restrict__ x)
{
    __shared__ __align__(16) unsigned short Vt[2][32 * 64];
    __shared__ __align__(16) float2 Bp[2136];   // (Bl[i], Bl[i+1]) pairs, 35x61 range
    __shared__ int ktab[196];                   // kidx at key granularity 4
    const int tid = threadIdx.x;
    const int lane = tid & 63, wid = tid >> 6;
    const int lo = lane & 15, hi = lane >> 4;
    // bid = h + 8*(b*4 + qt): all blocks of head h land on XCD h -> K/V L2-resident
    const int bid = blockIdx.x;
    const int h = bid & 7;
    const int t2 = bid >> 3;              // 0..63
    const int b = t2 >> 2;
    const int qt = t2 & 3;
    const int bh = b * 8 + h;
    const int q0 = qt * 224 + wid * 32;          // wave covers rows q0..q0+31
    const int blbase = (qt * 8 + 3) * 61;        // rel_y+30 range = [qt*8+3, qt*8+37]

    {
        const float* bsl = bias_t + h * 3721 + blbase;
        for (int i = tid; i < 2134; i += 448)
            Bp[i] = float2{ bsl[i], bsl[i + 1] };
        if (tid < 196) {
            int kc = tid * 4;                    // <= 780, ppos in-bounds
            ktab[tid] = ppos[2 * kc] * 61 + ppos[2 * kc + 1];
        }
    }

    bf16x8 qf0, qf1;
    int qb0, qb1;
    {
        int qr0 = q0 + lo;       if (qr0 > 783) qr0 = 783;   // clamp: tail rows compute
        int qr1 = q0 + 16 + lo;  if (qr1 > 783) qr1 = 783;   // row-783 data, unstored
        qf0 = *(const bf16x8*)(const void*)(qh + (((size_t)bh * NP) + qr0) * HD_ + hi * 8);
        qf1 = *(const bf16x8*)(const void*)(qh + (((size_t)bh * NP) + qr1) * HD_ + hi * 8);
        qb0 = cpos[qr0 * 2] * 61 + cpos[qr0 * 2 + 1] + 1860 - blbase;
        qb1 = cpos[qr1 * 2] * 61 + cpos[qr1 * 2 + 1] + 1860 - blbase;
    }

    const unsigned short* kbase = kh + (size_t)bh * NP * HD_;
    const unsigned short* vbase = vt + (size_t)bh * HD_ * NP;
    const int tv = tid - 192, sd = tv >> 3, ssg = tv & 7;
    bf16x8 vst = {};

    // V issue/stage (async split); overruns land in adjacent ws buffers, masked by P=0
    auto issue = [&](int kt) {
        if (tid >= 192)
            vst = *(const bf16x8*)(const void*)(vbase + sd * NP + kt * 64 + ssg * 8);
    };
    auto stage = [&](int buf) {
        if (tid >= 192) {
            int f = ssg >> 2;
            int j4 = ((ssg >> 1) & 1) * 4;
            int blkA = f * 4 + ((2 * ssg) & 3);
            int blkB = f * 4 + ((2 * ssg + 1) & 3);
            bf16x4 vlo = { vst[0], vst[1], vst[2], vst[3] };
            bf16x4 vhi = { vst[4], vst[5], vst[6], vst[7] };
            *(bf16x4*)(void*)(Vt[buf] + sd * 64 + ((blkA ^ (sd & 7)) * 8) + j4) = vlo;
            *(bf16x4*)(void*)(Vt[buf] + sd * 64 + ((blkB ^ (sd & 7)) * 8) + j4) = vhi;
        }
    };

    f32x4 o0[2] = {}, o1[2] = {};
    float lr0 = 0.f, lr1 = 0.f;

    issue(0);
    stage(0);
    for (int kt = 0; kt < 13; ++kt) {
        int cur = kt & 1;
        int k0 = kt * 64;
        if (kt < 12) issue(kt + 1);
        // K fragments straight from global (L2-resident, h-affine XCD)
        bf16x8 kf[4];
#pragma unroll
        for (int g = 0; g < 4; ++g)
            kf[g] = *(const bf16x8*)(const void*)(kbase + (size_t)(k0 + g * 16 + lo) * HD_ + hi * 8);
        __syncthreads();
        bool tail = (kt == 12);

        // ---- fragment 0 ----
        {
            f32x4 bc[4];
#pragma unroll
            for (int g = 0; g < 4; ++g) {
                if (tail && g > 0) {
                    bc[g] = f32x4{ -1e30f, -1e30f, -1e30f, -1e30f };
                } else {
                    int kbg = ktab[kt * 16 + g * 4 + hi];
                    int off = qb0 - kbg - 3;
                    float2 pA = Bp[off];
                    float2 pB = Bp[off + 2];
                    bc[g][0] = pB.y; bc[g][1] = pB.x; bc[g][2] = pA.y; bc[g][3] = pA.x;
                }
            }
            f32x4 s[4];
            __builtin_amdgcn_s_setprio(1);
#pragma unroll
            for (int g = 0; g < 4; ++g)
                s[g] = __builtin_amdgcn_mfma_f32_16x16x32_bf16(kf[g], qf0, bc[g], 0, 0, 0);
            __builtin_amdgcn_s_setprio(0);
            unsigned int c[4][2];
            float psum = 0.f;
#pragma unroll
            for (int g = 0; g < 4; ++g) {
                float p0 = fexp2(s[g][0]);
                float p1 = fexp2(s[g][1]);
                float p2 = fexp2(s[g][2]);
                float p3 = fexp2(s[g][3]);
                psum += (p0 + p1) + (p2 + p3);
                c[g][0] = cvtpk(p0, p1);
                c[g][1] = cvtpk(p2, p3);
            }
            lr0 += psum;
            __builtin_amdgcn_s_setprio(1);
#pragma unroll
            for (int f = 0; f < 2; ++f) {
                union { unsigned int u[4]; bf16x8 v; } pu;
                pu.u[0] = c[2 * f][0]; pu.u[1] = c[2 * f][1];
                pu.u[2] = c[2 * f + 1][0]; pu.u[3] = c[2 * f + 1][1];
#pragma unroll
                for (int cc = 0; cc < 2; ++cc) {
                    int d = cc * 16 + lo;
                    bf16x8 vf = *(const bf16x8*)(const void*)(Vt[cur] + d * 64 + (((f * 4 + hi) ^ (d & 7)) * 8));
                    o0[cc] = __builtin_amdgcn_mfma_f32_16x16x32_bf16(pu.v, vf, o0[cc], 0, 0, 0);
                }
            }
            __builtin_amdgcn_s_setprio(0);
        }
        // ---- fragment 1 ----
        {
            f32x4 bc[4];
#pragma unroll
            for (int g = 0; g < 4; ++g) {
                if (tail && g > 0) {
                    bc[g] = f32x4{ -1e30f, -1e30f, -1e30f, -1e30f };
                } else {
                    int kbg = ktab[kt * 16 + g * 4 + hi];
                    int off = qb1 - kbg - 3;
                    float2 pA = Bp[off];
                    float2 pB = Bp[off + 2];
                    bc[g][0] = pB.y; bc[g][1] = pB.x; bc[g][2] = pA.y; bc[g][3] = pA.x;
                }
            }
            f32x4 s[4];
            __builtin_amdgcn_s_setprio(1);
#pragma unroll
            for (int g = 0; g < 4; ++g)
                s[g] = __builtin_amdgcn_mfma_f32_16x16x32_bf16(kf[g], qf1, bc[g], 0, 0, 0);
            __builtin_amdgcn_s_setprio(0);
            unsigned int c[4][2];
            float psum = 0.f;
#pragma unroll
            for (int g = 0; g < 4; ++g) {
                float p0 = fexp2(s[g][0]);
                float p1 = fexp2(s[g][1]);
                float p2 = fexp2(s[g][2]);
                float p3 = fexp2(s[g][3]);
                psum += (p0 + p1) + (p2 + p3);
                c[g][0] = cvtpk(p0, p1);
                c[g][1] = cvtpk(p2, p3);
            }
            lr1 += psum;
            __builtin_amdgcn_s_setprio(1);
#pragma unroll
            for (int f = 0; f < 2; ++f) {
                union { unsigned int u[4]; bf16x8 v; } pu;
                pu.u[0] = c[2 * f][0]; pu.u[1] = c[2 * f][1];
                pu.u[2] = c[2 * f + 1][0]; pu.u[3] = c[2 * f + 1][1];
#pragma unroll
                for (int cc = 0; cc < 2; ++cc) {
                    int d = cc * 16 + lo;
                    bf16x8 vf = *(const bf16x8*)(const void*)(Vt[cur] + d * 64 + (((f * 4 + hi) ^ (d & 7)) * 8));
                    o1[cc] = __builtin_amdgcn_mfma_f32_16x16x32_bf16(pu.v, vf, o1[cc], 0, 0, 0);
                }
            }
            __builtin_amdgcn_s_setprio(0);
        }
        if (kt < 12) stage(cur ^ 1);
    }
    // final row-sum reduce + reciprocal + broadcast, per fragment
    lr0 += __shfl_xor(lr0, 16);
    lr0 += __shfl_xor(lr0, 32);
    lr1 += __shfl_xor(lr1, 16);
    lr1 += __shfl_xor(lr1, 32);
    float li0 = 1.0f / lr0, li1 = 1.0f / lr1;
    float lro0[4], lro1[4];
#pragma unroll
    for (int r = 0; r < 4; ++r) {
        lro0[r] = __shfl(li0, (lane & 48) | (hi * 4 + r));
        lro1[r] = __shfl(li1, (lane & 48) | (hi * 4 + r));
    }
#pragma unroll
    for (int cc = 0; cc < 2; ++cc)
#pragma unroll
        for (int r = 0; r < 4; ++r) {
            int qr = q0 + hi * 4 + r;
            if (qr < NP)
                x[((size_t)b * NP + qr) * D_ + h * HD_ + cc * 16 + lo] = f2bf(o0[cc][r] * lro0[r]);
            int qs = q0 + 16 + hi * 4 + r;
            if (qs < NP)
                x[((size_t)b * NP + qs) * D_ + h * HD_ + cc * 16 + lo] = f2bf(o1[cc][r] * lro1[r]);
        }
}

extern "C" void kernel_launch(void* const* d_in, const int* in_sizes, int n_in,
                              void* d_out, int out_size, void* d_ws, size_t ws_size,
                              hipStream_t stream)
{
    const float* cur    = (const float*)d_in[0];
    const float* prev   = (const float*)d_in[1];
    const float* conv_w = (const float*)d_in[2];
    const float* conv_b = (const float*)d_in[3];
    const float* q_w    = (const float*)d_in[4];
    const float* q_b    = (const float*)d_in[5];
    const float* kv_w   = (const float*)d_in[6];
    const float* kv_b   = (const float*)d_in[7];
    const float* proj_w = (const float*)d_in[8];
    const float* proj_b = (const float*)d_in[9];
    const float* btab   = (const float*)d_in[10];
    const int* cpos     = (const int*)d_in[11];
    const int* ppos     = (const int*)d_in[12];

    char* ws = (char*)d_ws;
    unsigned short* w_q    = (unsigned short*)(ws + 98304);
    unsigned short* w_kv   = (unsigned short*)(ws + 229376);
    unsigned short* w_pr   = (unsigned short*)(ws + 491520);
    float* bias_t          = (float*)(ws + 622592);             // 119072 B
    unsigned short* emb    = (unsigned short*)(ws + 10256384);  // 25088x256
    unsigned short* q_h    = (unsigned short*)(ws + 23101440);  // [bh][n][32]
    unsigned short* k_h    = (unsigned short*)(ws + 29523968);  // [bh][n][32]
    unsigned short* v_t    = (unsigned short*)(ws + 35946496);  // [bh][32][784]
    unsigned short* xb     = (unsigned short*)(ws + 42369024);  // [b][n][256]

    conv_prep<<<1157, 256, 0, stream>>>(cur, prev, conv_w, conv_b,
                                        q_w, kv_w, proj_w, w_q, w_kv, w_pr,
                                        btab, bias_t, emb);
    gemm_qkv<<<dim3(98, 6), 256, 0, stream>>>(emb, w_q, q_b, w_kv, kv_b, q_h, k_h, v_t);
    attn_k<<<512, 448, 0, stream>>>(q_h, k_h, v_t, bias_t, cpos, ppos, xb);
    gemm_px<<<dim3(392, 2), 256, 0, stream>>>(xb, w_pr, proj_b, (float*)d_out);

    (void)in_sizes; (void)n_in; (void)out_size; (void)ws_size;
}

// Round 14
// 73.446 us; speedup vs baseline: 1.0979x; 1.0979x over previous
//
#include <hip/hip_runtime.h>

#define B_ 16
#define NP 784
#define D_ 256
#define NH_ 8
#define HD_ 32
#define KEMB 192
#define SCALE_ 0.17677669529663687f
#define LOG2E_ 1.4426950408889634f

typedef __attribute__((ext_vector_type(4))) float f32x4;
typedef __attribute__((ext_vector_type(8))) short bf16x8;
typedef __attribute__((ext_vector_type(4))) short bf16x4;

__device__ __forceinline__ unsigned short f2bf(float f) {
    union { float f; unsigned int u; } v; v.f = f;
    unsigned int u = v.u;
    unsigned int r = (u + 0x7fffu + ((u >> 16) & 1u)) >> 16;
    return (unsigned short)r;
}

__device__ __forceinline__ unsigned int cvtpk(float a, float b) {
    unsigned int r;
    asm("v_cvt_pk_bf16_f32 %0, %1, %2" : "=v"(r) : "v"(a), "v"(b));
    return r;
}

__device__ __forceinline__ float fexp2(float x) {
#if __has_builtin(__builtin_amdgcn_exp2f)
    return __builtin_amdgcn_exp2f(x);
#else
    return exp2f(x);
#endif
}

// async global->LDS, 16B per lane; LDS dest = wave-uniform base + lane*16
__device__ __forceinline__ void gl_lds16(const unsigned short* g, unsigned short* l) {
    __builtin_amdgcn_global_load_lds(
        (const __attribute__((address_space(1))) unsigned int*)(const void*)g,
        (__attribute__((address_space(3))) unsigned int*)(void*)l, 16, 0, 0);
}

// ---------------- conv GEMM + prep tails: grid (1157) ----------------
__global__ __launch_bounds__(256) void conv_prep(
    const float* __restrict__ cur, const float* __restrict__ prev,
    const float* __restrict__ conv_w32, const float* __restrict__ bias,
    const float* __restrict__ q_w32, const float* __restrict__ kv_w32,
    const float* __restrict__ pr_w32,
    unsigned short* __restrict__ w_q, unsigned short* __restrict__ w_kv,
    unsigned short* __restrict__ w_pr,
    const float* __restrict__ bt, float* __restrict__ bto,
    unsigned short* __restrict__ outp)
{
    const int tid = threadIdx.x;
    if (blockIdx.x >= 784) {
        int bi = blockIdx.x - 784;
        if (bi < 256) {
            int i = (bi * 256 + tid) * 4;          // 262144 floats total
            const float* s; unsigned short* dp; int off;
            if (i < 65536)       { s = q_w32;  dp = w_q;  off = i; }
            else if (i < 196608) { s = kv_w32; dp = w_kv; off = i - 65536; }
            else                 { s = pr_w32; dp = w_pr; off = i - 196608; }
            float4 v = *(const float4*)(s + off);
            dp[off + 0] = f2bf(v.x); dp[off + 1] = f2bf(v.y);
            dp[off + 2] = f2bf(v.z); dp[off + 3] = f2bf(v.w);
        } else {
            int i = (bi - 256) * 256 + tid;        // < 29952
            if (i < 29768) {
                int h = i / 3721, idx = i - h * 3721;
                bto[i] = bt[idx * NH_ + h] * LOG2E_;
            }
        }
        return;
    }
    __shared__ __align__(16) unsigned short At[32 * 64];
    __shared__ __align__(16) unsigned short Bt[256 * 64];
    const int lane = tid & 63, wid = tid >> 6;
    const int lo = lane & 15, hi = lane >> 4;
    const int m0 = blockIdx.x * 32;
    // hoisted im2col A-source address (1 task/thread)
    const float* asrc;
    unsigned short* adst;
    {
        int row = tid >> 3, seg = tid & 7;
        int m = m0 + row;
        int fb = m / NP, n = m - fb * NP;
        int py = n / 28, px = n - py * 28;
        const float* F = (fb >= 16 ? prev + (size_t)(fb - 16) * 150528 : cur + (size_t)fb * 150528);
        asrc = F + (py * 8 + seg) * 224 + px * 8;
        adst = At + row * 64 + ((seg ^ (row & 7)) * 8);
    }
    f32x4 acc[2][4] = {};
#pragma unroll
    for (int kt = 0; kt < 3; ++kt) {
        __syncthreads();
        // B: 256x64 panel from fp32 weights, reg-staged + cvt
#pragma unroll
        for (int i = 0; i < 8; ++i) {
            int s = i * 256 + tid;
            int row = s >> 3, j = s & 7, seg = j ^ (row & 7);
            const float* wsrc = conv_w32 + row * KEMB + kt * 64 + seg * 8;
            float4 b0 = *(const float4*)(wsrc);
            float4 b1 = *(const float4*)(wsrc + 4);
            union { unsigned int u[4]; bf16x8 v; } bv;
            bv.u[0] = cvtpk(b0.x, b0.y); bv.u[1] = cvtpk(b0.z, b0.w);
            bv.u[2] = cvtpk(b1.x, b1.y); bv.u[3] = cvtpk(b1.z, b1.w);
            *(bf16x8*)(void*)(Bt + row * 64 + j * 8) = bv.v;
        }
        // A: reg-staged from frames (channel kt), swizzled ds_write
        {
            const float* src = asrc + kt * 50176;
            float4 a0 = *(const float4*)(src);
            float4 a1 = *(const float4*)(src + 4);
            union { unsigned int u[4]; bf16x8 v; } ov;
            ov.u[0] = cvtpk(a0.x, a0.y); ov.u[1] = cvtpk(a0.z, a0.w);
            ov.u[2] = cvtpk(a1.x, a1.y); ov.u[3] = cvtpk(a1.z, a1.w);
            *(bf16x8*)(void*)(adst) = ov.v;
        }
        __syncthreads();
#pragma unroll
        for (int kk = 0; kk < 2; ++kk) {
            bf16x8 af[2], bfv[4];
#pragma unroll
            for (int f = 0; f < 2; ++f) {
                int rowa = f * 16 + lo;
                af[f] = *(const bf16x8*)(const void*)(At + rowa * 64 + (((kk * 4 + hi) ^ (rowa & 7)) * 8));
            }
#pragma unroll
            for (int f = 0; f < 4; ++f) {
                int rowb = wid * 64 + f * 16 + lo;
                bfv[f] = *(const bf16x8*)(const void*)(Bt + rowb * 64 + (((kk * 4 + hi) ^ (rowb & 7)) * 8));
            }
#pragma unroll
            for (int fr = 0; fr < 2; ++fr)
#pragma unroll
                for (int fc = 0; fc < 4; ++fc)
                    acc[fr][fc] = __builtin_amdgcn_mfma_f32_16x16x32_bf16(af[fr], bfv[fc], acc[fr][fc], 0, 0, 0);
        }
    }
#pragma unroll
    for (int fr = 0; fr < 2; ++fr)
#pragma unroll
        for (int fc = 0; fc < 4; ++fc)
#pragma unroll
            for (int r = 0; r < 4; ++r) {
                int m = m0 + fr * 16 + hi * 4 + r;
                int c = wid * 64 + fc * 16 + lo;
                outp[(size_t)m * D_ + c] = f2bf(acc[fr][fc][r] + bias[c]);
            }
}

// ---------------- fused Q + KV projection: 128^2 tile, grid (98, 6) ----------------
__global__ __launch_bounds__(256) void gemm_qkv(
    const unsigned short* __restrict__ emb,
    const unsigned short* __restrict__ w_q, const float* __restrict__ q_b,
    const unsigned short* __restrict__ w_kv, const float* __restrict__ kv_b,
    unsigned short* __restrict__ q_h, unsigned short* __restrict__ k_h,
    unsigned short* __restrict__ v_t)
{
    __shared__ __align__(16) unsigned short At[128 * 64];
    __shared__ __align__(16) unsigned short Bt[128 * 64];
    const int tid = threadIdx.x;
    const int lo = tid & 15, hi = (tid >> 4) & 3, wid = tid >> 6;
    const int m0 = blockIdx.x * 128;
    const int y = blockIdx.y;
    const bool iskv = y >= 2;
    const unsigned short* Abase = iskv ? emb + (size_t)12544 * D_ : emb;   // kv uses PREV-frame emb
    const unsigned short* W = iskv ? w_kv : w_q;
    const float* bias = iskv ? kv_b : q_b;
    const int n0 = (iskv ? y - 2 : y) * 128;
    const int wr = wid >> 1, wc = wid & 1;
    const int wvb = wid * 512;
    f32x4 acc[4][4] = {};
#pragma unroll
    for (int kt = 0; kt < 4; ++kt) {
        const int k0 = kt * 64;
        __syncthreads();
#pragma unroll
        for (int i = 0; i < 4; ++i) {
            int s = i * 256 + tid;
            int row = s >> 3, seg = (s & 7) ^ (row & 7);
            gl_lds16(Abase + (size_t)(m0 + row) * D_ + k0 + seg * 8, At + i * 2048 + wvb);
            gl_lds16(W + (size_t)(n0 + row) * D_ + k0 + seg * 8, Bt + i * 2048 + wvb);
        }
        __syncthreads();
#pragma unroll
        for (int kk = 0; kk < 2; ++kk) {
            bf16x8 af[4], bfv[4];
#pragma unroll
            for (int f = 0; f < 4; ++f) {
                int rowa = wr * 64 + f * 16 + lo;
                af[f] = *(const bf16x8*)(const void*)(At + rowa * 64 + (((kk * 4 + hi) ^ (rowa & 7)) * 8));
                int rowb = wc * 64 + f * 16 + lo;
                bfv[f] = *(const bf16x8*)(const void*)(Bt + rowb * 64 + (((kk * 4 + hi) ^ (rowb & 7)) * 8));
            }
#pragma unroll
            for (int fr = 0; fr < 4; ++fr)
#pragma unroll
                for (int fc = 0; fc < 4; ++fc)
                    acc[fr][fc] = __builtin_amdgcn_mfma_f32_16x16x32_bf16(af[fr], bfv[fc], acc[fr][fc], 0, 0, 0);
        }
    }
#pragma unroll
    for (int fr = 0; fr < 4; ++fr)
#pragma unroll
        for (int fc = 0; fc < 4; ++fc)
#pragma unroll
            for (int r = 0; r < 4; ++r) {
                int m = m0 + wr * 64 + fr * 16 + hi * 4 + r;
                int c = n0 + wc * 64 + fc * 16 + lo;
                float val = acc[fr][fc][r] + bias[c];
                int b = m / NP, n = m - (m / NP) * NP;
                if (!iskv) {
                    int h = c >> 5, d = c & 31;
                    q_h[(((size_t)(b * NH_ + h)) * NP + n) * HD_ + d] = f2bf(val * (SCALE_ * LOG2E_));
                } else if (c < D_) {
                    int h = c >> 5, d = c & 31;
                    k_h[(((size_t)(b * NH_ + h)) * NP + n) * HD_ + d] = f2bf(val);
                } else {
                    int cc = c - D_; int h = cc >> 5, d = cc & 31;
                    v_t[(((size_t)(b * NH_ + h)) * HD_ + d) * NP + n] = f2bf(val);
                }
            }
}

// ---------------- proj GEMM: 32M x 128N tile, fp32 out, grid (392, 2) ----------------
__global__ __launch_bounds__(256) void gemm_px(
    const unsigned short* __restrict__ A, const unsigned short* __restrict__ W,
    const float* __restrict__ bias, float* __restrict__ outp)
{
    __shared__ __align__(16) unsigned short At[32 * 64];
    __shared__ __align__(16) unsigned short Bt[128 * 64];
    const int tid = threadIdx.x;
    const int lo = tid & 15, hi = (tid >> 4) & 3, wid = tid >> 6;
    const int m0 = blockIdx.x * 32, n0 = blockIdx.y * 128;
    const int wr = wid >> 1, wc = wid & 1;
    const int wvb = wid * 512;
    f32x4 acc[4] = {};
#pragma unroll
    for (int kt = 0; kt < 4; ++kt) {
        const int k0 = kt * 64;
        __syncthreads();
        {
            int row = tid >> 3, seg = (tid & 7) ^ ((tid >> 3) & 7);
            gl_lds16(A + (size_t)(m0 + row) * D_ + k0 + seg * 8, At + wvb);
        }
#pragma unroll
        for (int i = 0; i < 4; ++i) {
            int s = i * 256 + tid;
            int row = s >> 3, seg = (s & 7) ^ (row & 7);
            gl_lds16(W + (size_t)(n0 + row) * D_ + k0 + seg * 8, Bt + i * 2048 + wvb);
        }
        __syncthreads();
#pragma unroll
        for (int kk = 0; kk < 2; ++kk) {
            bf16x8 af, bfv[4];
            {
                int rowa = wr * 16 + lo;
                af = *(const bf16x8*)(const void*)(At + rowa * 64 + (((kk * 4 + hi) ^ (rowa & 7)) * 8));
            }
#pragma unroll
            for (int f = 0; f < 4; ++f) {
                int rowb = wc * 64 + f * 16 + lo;
                bfv[f] = *(const bf16x8*)(const void*)(Bt + rowb * 64 + (((kk * 4 + hi) ^ (rowb & 7)) * 8));
            }
#pragma unroll
            for (int fc = 0; fc < 4; ++fc)
                acc[fc] = __builtin_amdgcn_mfma_f32_16x16x32_bf16(af, bfv[fc], acc[fc], 0, 0, 0);
        }
    }
#pragma unroll
    for (int fc = 0; fc < 4; ++fc)
#pragma unroll
        for (int r = 0; r < 4; ++r) {
            int m = m0 + wr * 16 + hi * 4 + r;
            int c = n0 + wc * 64 + fc * 16 + lo;
            outp[(size_t)m * D_ + c] = acc[fc][r] + bias[c];
        }
}

// ---------------- attention: q-doubled waves (32 rows/wave), grid 512 ----------------
// R10-verified structure (K from global, V double-buffered LDS, 13 barriers), each
// wave owns TWO Q fragments: kf loads and block init amortize over 2x the MFMAs.
// Blocks per (b,h): 4 (qt 0..3, 224 rows each; qt=3 tail rows >=784 clamped+unstored).
__global__ __launch_bounds__(448) void attn_k(
    const unsigned short* __restrict__ qh, const unsigned short* __restrict__ kh,
    const unsigned short* __restrict__ vt, const float* __restrict__ bias_t,
    const int* __restrict__ cpos, const int* __restrict__ ppos,
    unsigned short* __restrict__ x)
{
    __shared__ __align__(16) unsigned short Vt[2][32 * 64];
    __shared__ __align__(16) float2 Bp[2136];   // (Bl[i], Bl[i+1]) pairs, 35x61 range
    __shared__ int ktab[196];                   // kidx at key granularity 4
    const int tid = threadIdx.x;
    const int lane = tid & 63, wid = tid >> 6;
    const int lo = lane & 15, hi = lane >> 4;
    // bid = h + 8*(b*4 + qt): all blocks of head h land on XCD h -> K/V L2-resident
    const int bid = blockIdx.x;
    const int h = bid & 7;
    const int t2 = bid >> 3;              // 0..63
    const int b = t2 >> 2;
    const int qt = t2 & 3;
    const int bh = b * 8 + h;
    const int q0 = qt * 224 + wid * 32;          // wave covers rows q0..q0+31
    const int blbase = (qt * 8 + 3) * 61;        // rel_y+30 range = [qt*8+3, qt*8+37]

    {
        const float* bsl = bias_t + h * 3721 + blbase;
        for (int i = tid; i < 2134; i += 448)
            Bp[i] = float2{ bsl[i], bsl[i + 1] };
        if (tid < 196) {
            int kc = tid * 4;                    // <= 780, ppos in-bounds
            ktab[tid] = ppos[2 * kc] * 61 + ppos[2 * kc + 1];
        }
    }

    bf16x8 qf0, qf1;
    int qb0, qb1;
    {
        int qr0 = q0 + lo;       if (qr0 > 783) qr0 = 783;   // clamp: tail rows compute
        int qr1 = q0 + 16 + lo;  if (qr1 > 783) qr1 = 783;   // row-783 data, unstored
        qf0 = *(const bf16x8*)(const void*)(qh + (((size_t)bh * NP) + qr0) * HD_ + hi * 8);
        qf1 = *(const bf16x8*)(const void*)(qh + (((size_t)bh * NP) + qr1) * HD_ + hi * 8);
        qb0 = cpos[qr0 * 2] * 61 + cpos[qr0 * 2 + 1] + 1860 - blbase;
        qb1 = cpos[qr1 * 2] * 61 + cpos[qr1 * 2 + 1] + 1860 - blbase;
    }

    const unsigned short* kbase = kh + (size_t)bh * NP * HD_;
    const unsigned short* vbase = vt + (size_t)bh * HD_ * NP;
    const int tv = tid - 192, sd = tv >> 3, ssg = tv & 7;
    bf16x8 vst = {};

    // V issue/stage (async split); overruns land in adjacent ws buffers, masked by P=0
    auto issue = [&](int kt) {
        if (tid >= 192)
            vst = *(const bf16x8*)(const void*)(vbase + sd * NP + kt * 64 + ssg * 8);
    };
    auto stage = [&](int buf) {
        if (tid >= 192) {
            int f = ssg >> 2;
            int j4 = ((ssg >> 1) & 1) * 4;
            int blkA = f * 4 + ((2 * ssg) & 3);
            int blkB = f * 4 + ((2 * ssg + 1) & 3);
            bf16x4 vlo = { vst[0], vst[1], vst[2], vst[3] };
            bf16x4 vhi = { vst[4], vst[5], vst[6], vst[7] };
            *(bf16x4*)(void*)(Vt[buf] + sd * 64 + ((blkA ^ (sd & 7)) * 8) + j4) = vlo;
            *(bf16x4*)(void*)(Vt[buf] + sd * 64 + ((blkB ^ (sd & 7)) * 8) + j4) = vhi;
        }
    };

    f32x4 o0[2] = {}, o1[2] = {};
    float lr0 = 0.f, lr1 = 0.f;

    issue(0);
    stage(0);
    for (int kt = 0; kt < 13; ++kt) {
        int cur = kt & 1;
        int k0 = kt * 64;
        if (kt < 12) issue(kt + 1);
        // K fragments straight from global (L2-resident, h-affine XCD)
        bf16x8 kf[4];
#pragma unroll
        for (int g = 0; g < 4; ++g)
            kf[g] = *(const bf16x8*)(const void*)(kbase + (size_t)(k0 + g * 16 + lo) * HD_ + hi * 8);
        __syncthreads();
        bool tail = (kt == 12);

        // ---- fragment 0 ----
        {
            f32x4 bc[4];
#pragma unroll
            for (int g = 0; g < 4; ++g) {
                if (tail && g > 0) {
                    bc[g] = f32x4{ -1e30f, -1e30f, -1e30f, -1e30f };
                } else {
                    int kbg = ktab[kt * 16 + g * 4 + hi];
                    int off = qb0 - kbg - 3;
                    float2 pA = Bp[off];
                    float2 pB = Bp[off + 2];
                    bc[g][0] = pB.y; bc[g][1] = pB.x; bc[g][2] = pA.y; bc[g][3] = pA.x;
                }
            }
            f32x4 s[4];
#pragma unroll
            for (int g = 0; g < 4; ++g)
                s[g] = __builtin_amdgcn_mfma_f32_16x16x32_bf16(kf[g], qf0, bc[g], 0, 0, 0);
            unsigned int c[4][2];
            float psum = 0.f;
#pragma unroll
            for (int g = 0; g < 4; ++g) {
                float p0 = fexp2(s[g][0]);
                float p1 = fexp2(s[g][1]);
                float p2 = fexp2(s[g][2]);
                float p3 = fexp2(s[g][3]);
                psum += (p0 + p1) + (p2 + p3);
                c[g][0] = cvtpk(p0, p1);
                c[g][1] = cvtpk(p2, p3);
            }
            lr0 += psum;
#pragma unroll
            for (int f = 0; f < 2; ++f) {
                union { unsigned int u[4]; bf16x8 v; } pu;
                pu.u[0] = c[2 * f][0]; pu.u[1] = c[2 * f][1];
                pu.u[2] = c[2 * f + 1][0]; pu.u[3] = c[2 * f + 1][1];
#pragma unroll
                for (int cc = 0; cc < 2; ++cc) {
                    int d = cc * 16 + lo;
                    bf16x8 vf = *(const bf16x8*)(const void*)(Vt[cur] + d * 64 + (((f * 4 + hi) ^ (d & 7)) * 8));
                    o0[cc] = __builtin_amdgcn_mfma_f32_16x16x32_bf16(pu.v, vf, o0[cc], 0, 0, 0);
                }
            }
        }
        // ---- fragment 1 ----
        {
            f32x4 bc[4];
#pragma unroll
            for (int g = 0; g < 4; ++g) {
                if (tail && g > 0) {
                    bc[g] = f32x4{ -1e30f, -1e30f, -1e30f, -1e30f };
                } else {
                    int kbg = ktab[kt * 16 + g * 4 + hi];
                    int off = qb1 - kbg - 3;
                    float2 pA = Bp[off];
                    float2 pB = Bp[off + 2];
                    bc[g][0] = pB.y; bc[g][1] = pB.x; bc[g][2] = pA.y; bc[g][3] = pA.x;
                }
            }
            f32x4 s[4];
#pragma unroll
            for (int g = 0; g < 4; ++g)
                s[g] = __builtin_amdgcn_mfma_f32_16x16x32_bf16(kf[g], qf1, bc[g], 0, 0, 0);
            unsigned int c[4][2];
            float psum = 0.f;
#pragma unroll
            for (int g = 0; g < 4; ++g) {
                float p0 = fexp2(s[g][0]);
                float p1 = fexp2(s[g][1]);
                float p2 = fexp2(s[g][2]);
                float p3 = fexp2(s[g][3]);
                psum += (p0 + p1) + (p2 + p3);
                c[g][0] = cvtpk(p0, p1);
                c[g][1] = cvtpk(p2, p3);
            }
            lr1 += psum;
#pragma unroll
            for (int f = 0; f < 2; ++f) {
                union { unsigned int u[4]; bf16x8 v; } pu;
                pu.u[0] = c[2 * f][0]; pu.u[1] = c[2 * f][1];
                pu.u[2] = c[2 * f + 1][0]; pu.u[3] = c[2 * f + 1][1];
#pragma unroll
                for (int cc = 0; cc < 2; ++cc) {
                    int d = cc * 16 + lo;
                    bf16x8 vf = *(const bf16x8*)(const void*)(Vt[cur] + d * 64 + (((f * 4 + hi) ^ (d & 7)) * 8));
                    o1[cc] = __builtin_amdgcn_mfma_f32_16x16x32_bf16(pu.v, vf, o1[cc], 0, 0, 0);
                }
            }
        }
        if (kt < 12) stage(cur ^ 1);
    }
    // final row-sum reduce + reciprocal + broadcast, per fragment
    lr0 += __shfl_xor(lr0, 16);
    lr0 += __shfl_xor(lr0, 32);
    lr1 += __shfl_xor(lr1, 16);
    lr1 += __shfl_xor(lr1, 32);
    float li0 = 1.0f / lr0, li1 = 1.0f / lr1;
    float lro0[4], lro1[4];
#pragma unroll
    for (int r = 0; r < 4; ++r) {
        lro0[r] = __shfl(li0, (lane & 48) | (hi * 4 + r));
        lro1[r] = __shfl(li1, (lane & 48) | (hi * 4 + r));
    }
#pragma unroll
    for (int cc = 0; cc < 2; ++cc)
#pragma unroll
        for (int r = 0; r < 4; ++r) {
            int qr = q0 + hi * 4 + r;
            if (qr < NP)
                x[((size_t)b * NP + qr) * D_ + h * HD_ + cc * 16 + lo] = f2bf(o0[cc][r] * lro0[r]);
            int qs = q0 + 16 + hi * 4 + r;
            if (qs < NP)
                x[((size_t)b * NP + qs) * D_ + h * HD_ + cc * 16 + lo] = f2bf(o1[cc][r] * lro1[r]);
        }
}

extern "C" void kernel_launch(void* const* d_in, const int* in_sizes, int n_in,
                              void* d_out, int out_size, void* d_ws, size_t ws_size,
                              hipStream_t stream)
{
    const float* cur    = (const float*)d_in[0];
    const float* prev   = (const float*)d_in[1];
    const float* conv_w = (const float*)d_in[2];
    const float* conv_b = (const float*)d_in[3];
    const float* q_w    = (const float*)d_in[4];
    const float* q_b    = (const float*)d_in[5];
    const float* kv_w   = (const float*)d_in[6];
    const float* kv_b   = (const float*)d_in[7];
    const float* proj_w = (const float*)d_in[8];
    const float* proj_b = (const float*)d_in[9];
    const float* btab   = (const float*)d_in[10];
    const int* cpos     = (const int*)d_in[11];
    const int* ppos     = (const int*)d_in[12];

    char* ws = (char*)d_ws;
    unsigned short* w_q    = (unsigned short*)(ws + 98304);
    unsigned short* w_kv   = (unsigned short*)(ws + 229376);
    unsigned short* w_pr   = (unsigned short*)(ws + 491520);
    float* bias_t          = (float*)(ws + 622592);             // 119072 B
    unsigned short* emb    = (unsigned short*)(ws + 10256384);  // 25088x256
    unsigned short* q_h    = (unsigned short*)(ws + 23101440);  // [bh][n][32]
    unsigned short* k_h    = (unsigned short*)(ws + 29523968);  // [bh][n][32]
    unsigned short* v_t    = (unsigned short*)(ws + 35946496);  // [bh][32][784]
    unsigned short* xb     = (unsigned short*)(ws + 42369024);  // [b][n][256]

    conv_prep<<<1157, 256, 0, stream>>>(cur, prev, conv_w, conv_b,
                                        q_w, kv_w, proj_w, w_q, w_kv, w_pr,
                                        btab, bias_t, emb);
    gemm_qkv<<<dim3(98, 6), 256, 0, stream>>>(emb, w_q, q_b, w_kv, kv_b, q_h, k_h, v_t);
    attn_k<<<512, 448, 0, stream>>>(q_h, k_h, v_t, bias_t, cpos, ppos, xb);
    gemm_px<<<dim3(392, 2), 256, 0, stream>>>(xb, w_pr, proj_b, (float*)d_out);

    (void)in_sizes; (void)n_in; (void)out_size; (void)ws_size;
}